// Round 13
// baseline (495.437 us; speedup 1.0000x reference)
//
#include <hip/hip_runtime.h>
#include <hip/hip_fp16.h>
#include <math.h>

#define NB   16     // batch
#define IMG  128    // input image side
#define NANG 300
#define NDET 300
#define WB   148    // canvas live box: x,y in [76,224)
#define GRID 768    // 3 blocks/CU x 256 CUs -- co-resident by __launch_bounds__(256,3)
#define MAGICW 0x13579BDFu

typedef _Float16 v2h __attribute__((ext_vector_type(2)));

// Gaussian taps: sigma_img -> 2^(-d^2/2); sigma_att -> 2^(-d^2/8). f64 normalize, f32 cast.
__device__ __constant__ float KE[9] = {
  (float)(0.00390625            / 3.0104144100214136),
  (float)(0.04419417382415922   / 3.0104144100214136),
  (float)(0.25                  / 3.0104144100214136),
  (float)(0.7071067811865476    / 3.0104144100214136),
  (float)(1.0                   / 3.0104144100214136),
  (float)(0.7071067811865476    / 3.0104144100214136),
  (float)(0.25                  / 3.0104144100214136),
  (float)(0.04419417382415922   / 3.0104144100214136),
  (float)(0.00390625            / 3.0104144100214136)
};
__device__ __constant__ float KA[17] = {
  (float)(0.00390625            / 6.019333926786741),
  (float)(0.014328188175072987  / 6.019333926786741),
  (float)(0.04419417382415922   / 6.019333926786741),
  (float)(0.11462550540058389   / 6.019333926786741),
  (float)(0.25                  / 6.019333926786741),
  (float)(0.4585020216023356    / 6.019333926786741),
  (float)(0.7071067811865476    / 6.019333926786741),
  (float)(0.9170040432046712    / 6.019333926786741),
  (float)(1.0                   / 6.019333926786741),
  (float)(0.9170040432046712    / 6.019333926786741),
  (float)(0.7071067811865476    / 6.019333926786741),
  (float)(0.4585020216023356    / 6.019333926786741),
  (float)(0.25                  / 6.019333926786741),
  (float)(0.11462550540058389   / 6.019333926786741),
  (float)(0.04419417382415922   / 6.019333926786741),
  (float)(0.014328188175072987  / 6.019333926786741),
  (float)(0.00390625            / 6.019333926786741)
};

__device__ __forceinline__ unsigned h16(float f) {
  return (unsigned)__half_as_ushort(__float2half_rn(f));
}
__device__ __forceinline__ unsigned pk16u(float a, float b) {
  return __builtin_bit_cast(unsigned, __builtin_amdgcn_cvt_pkrtz(a, b));
}
__device__ __forceinline__ float fdot2(unsigned q, unsigned w, float acc) {
  return __builtin_amdgcn_fdot2(__builtin_bit_cast(v2h, q), __builtin_bit_cast(v2h, w), acc, false);
}

// Grid-wide barrier: canonical arrive+spin on a device-scope counter. All GRID
// blocks are co-resident (launch_bounds guarantees 3 blocks/CU), so spinning is
// deadlock-free. Release on arrive publishes this XCD's L2 (buffer_wbl2);
// acquire on the spin load invalidates the consumer's (buffer_inv) -- the G16
// cross-XCD visibility requirement.
__device__ __forceinline__ void gridbar(unsigned* cnt) {
  __syncthreads();
  if (threadIdx.x == 0) {
    __hip_atomic_fetch_add(cnt, 1u, __ATOMIC_ACQ_REL, __HIP_MEMORY_SCOPE_AGENT);
    while (__hip_atomic_load(cnt, __ATOMIC_ACQUIRE, __HIP_MEMORY_SCOPE_AGENT) < (unsigned)GRID)
      __builtin_amdgcn_s_sleep(1);
  }
  __syncthreads();
}

// ONE persistent kernel, three phases separated by grid barriers:
//  P1 prep : fused pad+blur -> f16 quad canvas Q[y'][x'][b] = uint4{E00|E01,
//            E10|E11, A00|A01, A10|A11} (f16 pairs, A pre-scaled 0.01) over the
//            live box [76,224)^2. 1600 tiles, grid-strided.
//  P2 radon: wave-local LDS coordinate pipeline (see r12): Phase A computes 16
//            coords/weights across lanes, Phase B does broadcast ds_read_b128 +
//            one dwordx4/sample + 4 fdot2. Coordinate clamp px,py->[76.5,222.0]
//            before floor: identity in-chord; clamped samples land on all-zero
//            rows/cols {76,77,222,223} -> exact 0, addresses in-bounds.
//  P3 dblur: per-angle 5-tap detector blur (reflect) + scale -> out[b][a][j].
__global__ void __launch_bounds__(256, 3)
k_fused(const float* __restrict__ img, const float* __restrict__ att,
        const float* __restrict__ scale, uint4* __restrict__ Q,
        float* __restrict__ S, unsigned* __restrict__ W,
        float* __restrict__ out) {
  __shared__ float sm[2704];            // P1: 10.8 KB staging ; P2: 4.35 KB coord pipe
  int tid = threadIdx.x;
  int vb  = blockIdx.x;

  // Init protocol: ws is poisoned 0xAA before every launch. Block 0 zeroes the
  // two barrier counters, then publishes MAGICW; everyone waits for MAGICW
  // before first use of the counters. Co-residency makes the wait safe.
  if (tid == 0) {
    if (vb == 0) {
      __hip_atomic_store(W + 1, 0u, __ATOMIC_RELAXED, __HIP_MEMORY_SCOPE_AGENT);
      __hip_atomic_store(W + 3, 0u, __ATOMIC_RELAXED, __HIP_MEMORY_SCOPE_AGENT);
      __hip_atomic_store(W + 0, MAGICW, __ATOMIC_RELEASE, __HIP_MEMORY_SCOPE_AGENT);
    }
    while (__hip_atomic_load(W + 0, __ATOMIC_ACQUIRE, __HIP_MEMORY_SCOPE_AGENT) != MAGICW)
      __builtin_amdgcn_s_sleep(1);
  }
  __syncthreads();

  // ---------------- Phase 1: prep (1600 tiles) ----------------
  {
    float* sImg = sm;                   // 625
    float* sAtt = sm + 625;             // 1089
    float* sEi  = sm + 1714;            // 425
    float* sAi  = sm + 2139;            // 561
    int tx = tid & 15, ty = tid >> 4;
    for (int vt = vb; vt < 1600; vt += GRID) {
      int X0 = (vt % 10) * 16;
      int Y0 = ((vt / 10) % 10) * 16;
      int b  = vt / 100;
      const float* imb = img + b * IMG * IMG;
      const float* atb = att + b * IMG * IMG;
      for (int u = tid; u < 625; u += 256) {
        int r = u / 25, cc = u - r * 25;
        int ir = Y0 - 14 + r, ic = X0 - 14 + cc;
        bool v = (ir >= 0) & (ir < IMG) & (ic >= 0) & (ic < IMG);
        sImg[u] = v ? imb[ir * IMG + ic] : 0.f;
      }
      for (int u = tid; u < 1089; u += 256) {
        int r = u / 33, cc = u - r * 33;
        int ir = Y0 - 18 + r, ic = X0 - 18 + cc;
        bool v = (ir >= 0) & (ir < IMG) & (ic >= 0) & (ic < IMG);
        sAtt[u] = v ? atb[ir * IMG + ic] : 0.f;
      }
      __syncthreads();
      for (int u = tid; u < 425; u += 256) {
        int r = u / 17, cc = u - r * 17;
        float acc = 0.f;
#pragma unroll
        for (int d = 0; d < 9; ++d) acc = fmaf(KE[d], sImg[r * 25 + cc + d], acc);
        sEi[u] = acc;
      }
      for (int u = tid; u < 561; u += 256) {
        int r = u / 17, cc = u - r * 17;
        float acc = 0.f;
#pragma unroll
        for (int d = 0; d < 17; ++d) acc = fmaf(KA[d], sAtt[r * 33 + cc + d], acc);
        sAi[u] = acc;
      }
      __syncthreads();
      int xc = X0 + tx, yc = Y0 + ty;
      if (xc < WB && yc < WB) {
        float E00 = 0.f, E01 = 0.f, E10 = 0.f, E11 = 0.f;
        float A00 = 0.f, A01 = 0.f, A10 = 0.f, A11 = 0.f;
#pragma unroll
        for (int d = 0; d < 9; ++d) {
          float k = KE[d];
          E00 = fmaf(k, sEi[(ty + d) * 17 + tx],     E00);
          E01 = fmaf(k, sEi[(ty + d) * 17 + tx + 1], E01);
          E10 = fmaf(k, sEi[(ty + 1 + d) * 17 + tx],     E10);
          E11 = fmaf(k, sEi[(ty + 1 + d) * 17 + tx + 1], E11);
        }
#pragma unroll
        for (int d = 0; d < 17; ++d) {
          float k = KA[d];
          A00 = fmaf(k, sAi[(ty + d) * 17 + tx],     A00);
          A01 = fmaf(k, sAi[(ty + d) * 17 + tx + 1], A01);
          A10 = fmaf(k, sAi[(ty + 1 + d) * 17 + tx],     A10);
          A11 = fmaf(k, sAi[(ty + 1 + d) * 17 + tx + 1], A11);
        }
        uint4 q;
        q.x = h16(E00) | (h16(E01) << 16);
        q.y = h16(E10) | (h16(E11) << 16);
        q.z = h16(0.01f * A00) | (h16(0.01f * A01) << 16);
        q.w = h16(0.01f * A10) | (h16(0.01f * A11) << 16);
        Q[(yc * WB + xc) * NB + b] = q;
      }
      __syncthreads();                  // protect LDS before next tile's stores
    }
  }
  gridbar(W + 1);

  // ---------------- Phase 2: radon (5700 tiles) ----------------
  {
    uint4* sLds = (uint4*)sm;           // row jrow*17 + u ; 17-stride
    int b    = tid & 15;
    int jrow = tid >> 4;
    uint4* entW0 = &sLds[jrow * 17];
    const char* Pcb = (const char*)Q + b * 16;
    const int PIXBASE = -76 * 149 * 256;

    for (int vt = vb; vt < 5700; vt += GRID) {
      int a = vt / 19;
      int j = (vt - a * 19) * 16 + jrow;
      bool jvalid = j < NDET;

      float th = (float)a * (float)(3.14159265358979323846 / 299.0);
      float c = cosf(th), s = sinf(th);
      float xj = fmaf((float)j, (float)(2.0 / 299.0), -1.0f);
      float pb = fmaf(c,  xj, 1.0f) * 149.5f - 149.5f * s;
      float qb = fmaf(-s, xj, 1.0f) * 149.5f - 149.5f * c;
      const float L = 76.5f, H = 222.5f;
      float lo = 0.f, hi = jvalid ? 299.0f : -1.0f;
      if (s > 1e-6f) {
        float inv = 1.0f / s;
        lo = fmaxf(lo, (L - pb) * inv); hi = fminf(hi, (H - pb) * inv);
      } else if (pb < L || pb > H) { hi = -1.f; }
      if (fabsf(c) > 1e-6f) {
        float inv = 1.0f / c;
        float t0 = (L - qb) * inv, t1 = (H - qb) * inv;
        lo = fmaxf(lo, fminf(t0, t1)); hi = fminf(hi, fmaxf(t0, t1));
      } else if (qb < L || qb > H) { hi = -1.f; }

      float lo_w = fminf(lo, __shfl_xor(lo, 16));
      lo_w = fminf(lo_w, __shfl_xor(lo_w, 32));
      float hi_w = fmaxf(hi, __shfl_xor(hi, 16));
      hi_w = fmaxf(hi_w, __shfl_xor(hi_w, 32));
      int i0w  = __builtin_amdgcn_readfirstlane((int)floorf(fmaxf(lo_w, 0.f)));
      int ihiw = __builtin_amdgcn_readfirstlane((int)floorf(hi_w));

      uint4* entW = entW0 + b;
      const uint4* entR = entW0;
      float sE0 = 0.f, sE1 = 0.f, sA0 = 0.f, sA1 = 0.f;
      float fib = (float)i0w + (float)b;

      for (int ib = i0w; ib <= ihiw; ib += 16, fib += 16.f) {
        {
          float px = fmaf(fib, s, pb);
          float py = fmaf(fib, c, qb);
          px = fminf(fmaxf(px, 76.5f), 222.0f);
          py = fminf(fmaxf(py, 76.5f), 222.0f);
          float x0f = floorf(px), y0f = floorf(py);
          float wx = px - x0f, wy = py - y0f;
          int idx = (int)fmaf(y0f, (float)WB, x0f);
          int off = (idx << 8) + PIXBASE;
          float omx = 1.0f - wx, omy = 1.0f - wy;
          unsigned w0 = pk16u(omy * omx, omy * wx);
          unsigned w1 = pk16u(wy * omx,  wy * wx);
          *entW = make_uint4((unsigned)off, w0, w1, w1);
        }
        __builtin_amdgcn_wave_barrier();
#pragma unroll
        for (int g = 0; g < 2; ++g) {
          uint4 e[8];
#pragma unroll
          for (int u = 0; u < 8; ++u) e[u] = entR[g * 8 + u];
          uint4 q[8];
#pragma unroll
          for (int u = 0; u < 8; ++u)
            q[u] = *(const uint4*)(Pcb + (int)e[u].x);
#pragma unroll
          for (int u = 0; u < 8; ++u) {
            sE0 = fdot2(q[u].x, e[u].y, sE0);
            sE1 = fdot2(q[u].y, e[u].z, sE1);
            sA0 = fdot2(q[u].z, e[u].y, sA0);
            sA1 = fdot2(q[u].w, e[u].z, sA1);
          }
        }
        __builtin_amdgcn_wave_barrier();
      }
      if (jvalid) {
        float sumE = sE0 + sE1, sumA = sA0 + sA1;
        S[(a * NB + b) * NDET + j] = sumE * expf(-2.0f * sumA);  // VOXEL_MM = 2
      }
    }
  }
  gridbar(W + 3);

  // ---------------- Phase 3: dblur (4800 tiles) ----------------
  {
    for (int vt = vb; vt < 4800; vt += GRID) {
      int a = vt % 300;
      int b = vt / 300;
      float th = (float)a * (float)(3.14159265358979323846 / 299.0);
      float c = cosf(th), s = sinf(th);
      float u = fabsf(c) + fabsf(s);    // bw = 2u
      float u2 = u * u;
      float e1 = exp2f(-2.0f * u2);
      float e2 = exp2f(-8.0f * u2);
      float norm = 1.0f / (1.0f + 2.0f * (e1 + e2));
      float w2c = norm, w1c = e1 * norm, w0c = e2 * norm;
      float sc = scale[b];
      const float* row = S + (a * NB + b) * NDET;
      float* orow = out + (b * NANG + a) * NDET;
      for (int j = tid; j < NDET; j += 256) {
        float acc = 0.f;
#pragma unroll
        for (int tt = -2; tt <= 2; ++tt) {
          int jr = j + tt;
          if (jr < 0) jr = -jr;
          if (jr > 299) jr = 598 - jr;
          float w = (tt == 0) ? w2c : ((tt == 1 || tt == -1) ? w1c : w0c);
          acc = fmaf(w, row[jr], acc);
        }
        orow[j] = acc * sc;
      }
    }
  }
}

extern "C" void kernel_launch(void* const* d_in, const int* in_sizes, int n_in,
                              void* d_out, int out_size, void* d_ws, size_t ws_size,
                              hipStream_t stream) {
  const float* img   = (const float*)d_in[0];
  const float* att   = (const float*)d_in[1];
  const float* scale = (const float*)d_in[2];
  float* out = (float*)d_out;
  float* ws  = (float*)d_ws;

  // ws layout (floats): Q 148*148*16 uint4 (5.61 MB) | S 300*300*16 (5.76 MB) | W barrier words
  uint4*    Q = (uint4*)ws;
  float*    S = ws + 1401856;
  unsigned* W = (unsigned*)(ws + 2841856);

  k_fused<<<dim3(GRID), 256, 0, stream>>>(img, att, scale, Q, S, W, out);
}

// Round 14
// 367.589 us; speedup vs baseline: 1.3478x; 1.3478x over previous
//
#include <hip/hip_runtime.h>
#include <hip/hip_fp16.h>
#include <hip/hip_cooperative_groups.h>
#include <math.h>

namespace cg = cooperative_groups;

#define NB   16     // batch
#define IMG  128    // input image side
#define NANG 300
#define NDET 300
#define WB   148    // canvas live box: x,y in [76,224)
#define GRID 768    // 3 blocks/CU x 256 CUs, co-resident via __launch_bounds__(256,3)

typedef _Float16 v2h __attribute__((ext_vector_type(2)));

// Gaussian taps: sigma_img -> 2^(-d^2/2); sigma_att -> 2^(-d^2/8). f64 normalize, f32 cast.
__device__ __constant__ float KE[9] = {
  (float)(0.00390625            / 3.0104144100214136),
  (float)(0.04419417382415922   / 3.0104144100214136),
  (float)(0.25                  / 3.0104144100214136),
  (float)(0.7071067811865476    / 3.0104144100214136),
  (float)(1.0                   / 3.0104144100214136),
  (float)(0.7071067811865476    / 3.0104144100214136),
  (float)(0.25                  / 3.0104144100214136),
  (float)(0.04419417382415922   / 3.0104144100214136),
  (float)(0.00390625            / 3.0104144100214136)
};
__device__ __constant__ float KA[17] = {
  (float)(0.00390625            / 6.019333926786741),
  (float)(0.014328188175072987  / 6.019333926786741),
  (float)(0.04419417382415922   / 6.019333926786741),
  (float)(0.11462550540058389   / 6.019333926786741),
  (float)(0.25                  / 6.019333926786741),
  (float)(0.4585020216023356    / 6.019333926786741),
  (float)(0.7071067811865476    / 6.019333926786741),
  (float)(0.9170040432046712    / 6.019333926786741),
  (float)(1.0                   / 6.019333926786741),
  (float)(0.9170040432046712    / 6.019333926786741),
  (float)(0.7071067811865476    / 6.019333926786741),
  (float)(0.4585020216023356    / 6.019333926786741),
  (float)(0.25                  / 6.019333926786741),
  (float)(0.11462550540058389   / 6.019333926786741),
  (float)(0.04419417382415922   / 6.019333926786741),
  (float)(0.014328188175072987  / 6.019333926786741),
  (float)(0.00390625            / 6.019333926786741)
};

__device__ __forceinline__ unsigned h16(float f) {
  return (unsigned)__half_as_ushort(__float2half_rn(f));
}
__device__ __forceinline__ unsigned pk16u(float a, float b) {
  return __builtin_bit_cast(unsigned, __builtin_amdgcn_cvt_pkrtz(a, b));
}
__device__ __forceinline__ float fdot2(unsigned q, unsigned w, float acc) {
  return __builtin_amdgcn_fdot2(__builtin_bit_cast(v2h, q), __builtin_bit_cast(v2h, w), acc, false);
}

// ---------- shared phase bodies (used by fused kernel and fallback kernels) ----------

// prep tile: fused pad+blur -> f16 quad canvas Q[y'][x'][b] = uint4{E00|E01,
// E10|E11, A00|A01, A10|A11} (f16 pairs, A pre-scaled 0.01) over box [76,224)^2.
__device__ __forceinline__ void prep_tile(const float* __restrict__ img,
                                          const float* __restrict__ att,
                                          uint4* __restrict__ Q,
                                          float* sm, int tid,
                                          int X0, int Y0, int b) {
  float* sImg = sm;                   // 625
  float* sAtt = sm + 625;             // 1089
  float* sEi  = sm + 1714;            // 425
  float* sAi  = sm + 2139;            // 561
  int tx = tid & 15, ty = tid >> 4;
  const float* imb = img + b * IMG * IMG;
  const float* atb = att + b * IMG * IMG;
  for (int u = tid; u < 625; u += 256) {
    int r = u / 25, cc = u - r * 25;
    int ir = Y0 - 14 + r, ic = X0 - 14 + cc;
    bool v = (ir >= 0) & (ir < IMG) & (ic >= 0) & (ic < IMG);
    sImg[u] = v ? imb[ir * IMG + ic] : 0.f;
  }
  for (int u = tid; u < 1089; u += 256) {
    int r = u / 33, cc = u - r * 33;
    int ir = Y0 - 18 + r, ic = X0 - 18 + cc;
    bool v = (ir >= 0) & (ir < IMG) & (ic >= 0) & (ic < IMG);
    sAtt[u] = v ? atb[ir * IMG + ic] : 0.f;
  }
  __syncthreads();
  for (int u = tid; u < 425; u += 256) {
    int r = u / 17, cc = u - r * 17;
    float acc = 0.f;
#pragma unroll
    for (int d = 0; d < 9; ++d) acc = fmaf(KE[d], sImg[r * 25 + cc + d], acc);
    sEi[u] = acc;
  }
  for (int u = tid; u < 561; u += 256) {
    int r = u / 17, cc = u - r * 17;
    float acc = 0.f;
#pragma unroll
    for (int d = 0; d < 17; ++d) acc = fmaf(KA[d], sAtt[r * 33 + cc + d], acc);
    sAi[u] = acc;
  }
  __syncthreads();
  int xc = X0 + tx, yc = Y0 + ty;
  if (xc < WB && yc < WB) {
    float E00 = 0.f, E01 = 0.f, E10 = 0.f, E11 = 0.f;
    float A00 = 0.f, A01 = 0.f, A10 = 0.f, A11 = 0.f;
#pragma unroll
    for (int d = 0; d < 9; ++d) {
      float k = KE[d];
      E00 = fmaf(k, sEi[(ty + d) * 17 + tx],     E00);
      E01 = fmaf(k, sEi[(ty + d) * 17 + tx + 1], E01);
      E10 = fmaf(k, sEi[(ty + 1 + d) * 17 + tx],     E10);
      E11 = fmaf(k, sEi[(ty + 1 + d) * 17 + tx + 1], E11);
    }
#pragma unroll
    for (int d = 0; d < 17; ++d) {
      float k = KA[d];
      A00 = fmaf(k, sAi[(ty + d) * 17 + tx],     A00);
      A01 = fmaf(k, sAi[(ty + d) * 17 + tx + 1], A01);
      A10 = fmaf(k, sAi[(ty + 1 + d) * 17 + tx],     A10);
      A11 = fmaf(k, sAi[(ty + 1 + d) * 17 + tx + 1], A11);
    }
    uint4 q;
    q.x = h16(E00) | (h16(E01) << 16);
    q.y = h16(E10) | (h16(E11) << 16);
    q.z = h16(0.01f * A00) | (h16(0.01f * A01) << 16);
    q.w = h16(0.01f * A10) | (h16(0.01f * A11) << 16);
    Q[(yc * WB + xc) * NB + b] = q;
  }
}

// radon tile (r12-validated): wave-local LDS coordinate pipeline. Phase A computes
// 16 coords/weights across lanes; Phase B: broadcast ds_read_b128 + one dwordx4 per
// sample + 4 fdot2. Coordinate clamp px,py->[76.5,222.0] before floor: identity
// in-chord; clamped samples hit all-zero rows/cols {76,77,222,223} -> exact 0.
__device__ __forceinline__ void radon_tile(const uint4* __restrict__ Q,
                                           float* __restrict__ S,
                                           uint4* sLds, int tid, int a, int jblk) {
  int b    = tid & 15;
  int jrow = tid >> 4;
  int j = jblk * 16 + jrow;
  bool jvalid = j < NDET;

  float th = (float)a * (float)(3.14159265358979323846 / 299.0);
  float c = cosf(th), s = sinf(th);
  float xj = fmaf((float)j, (float)(2.0 / 299.0), -1.0f);
  float pb = fmaf(c,  xj, 1.0f) * 149.5f - 149.5f * s;
  float qb = fmaf(-s, xj, 1.0f) * 149.5f - 149.5f * c;
  const float L = 76.5f, H = 222.5f;
  float lo = 0.f, hi = jvalid ? 299.0f : -1.0f;
  if (s > 1e-6f) {
    float inv = 1.0f / s;
    lo = fmaxf(lo, (L - pb) * inv); hi = fminf(hi, (H - pb) * inv);
  } else if (pb < L || pb > H) { hi = -1.f; }
  if (fabsf(c) > 1e-6f) {
    float inv = 1.0f / c;
    float t0 = (L - qb) * inv, t1 = (H - qb) * inv;
    lo = fmaxf(lo, fminf(t0, t1)); hi = fminf(hi, fmaxf(t0, t1));
  } else if (qb < L || qb > H) { hi = -1.f; }

  float lo_w = fminf(lo, __shfl_xor(lo, 16));
  lo_w = fminf(lo_w, __shfl_xor(lo_w, 32));
  float hi_w = fmaxf(hi, __shfl_xor(hi, 16));
  hi_w = fmaxf(hi_w, __shfl_xor(hi_w, 32));
  int i0w  = __builtin_amdgcn_readfirstlane((int)floorf(fmaxf(lo_w, 0.f)));
  int ihiw = __builtin_amdgcn_readfirstlane((int)floorf(hi_w));

  uint4* entW = &sLds[jrow * 17 + b];
  const uint4* entR = &sLds[jrow * 17];
  const char* Pcb = (const char*)Q + b * 16;
  const int PIXBASE = -76 * 149 * 256;

  float sE0 = 0.f, sE1 = 0.f, sA0 = 0.f, sA1 = 0.f;
  float fib = (float)i0w + (float)b;

  for (int ib = i0w; ib <= ihiw; ib += 16, fib += 16.f) {
    {
      float px = fmaf(fib, s, pb);
      float py = fmaf(fib, c, qb);
      px = fminf(fmaxf(px, 76.5f), 222.0f);
      py = fminf(fmaxf(py, 76.5f), 222.0f);
      float x0f = floorf(px), y0f = floorf(py);
      float wx = px - x0f, wy = py - y0f;
      int idx = (int)fmaf(y0f, (float)WB, x0f);
      int off = (idx << 8) + PIXBASE;
      float omx = 1.0f - wx, omy = 1.0f - wy;
      unsigned w0 = pk16u(omy * omx, omy * wx);
      unsigned w1 = pk16u(wy * omx,  wy * wx);
      *entW = make_uint4((unsigned)off, w0, w1, w1);
    }
    __builtin_amdgcn_wave_barrier();
#pragma unroll
    for (int g = 0; g < 2; ++g) {
      uint4 e[8];
#pragma unroll
      for (int u = 0; u < 8; ++u) e[u] = entR[g * 8 + u];
      uint4 q[8];
#pragma unroll
      for (int u = 0; u < 8; ++u)
        q[u] = *(const uint4*)(Pcb + (int)e[u].x);
#pragma unroll
      for (int u = 0; u < 8; ++u) {
        sE0 = fdot2(q[u].x, e[u].y, sE0);
        sE1 = fdot2(q[u].y, e[u].z, sE1);
        sA0 = fdot2(q[u].z, e[u].y, sA0);
        sA1 = fdot2(q[u].w, e[u].z, sA1);
      }
    }
    __builtin_amdgcn_wave_barrier();
  }
  if (jvalid) {
    float sumE = sE0 + sE1, sumA = sA0 + sA1;
    S[(a * NB + b) * NDET + j] = sumE * expf(-2.0f * sumA);  // VOXEL_MM = 2
  }
}

// dblur row: per-angle 5-tap detector blur (reflect) + scale -> out[b][a][j].
__device__ __forceinline__ void dblur_row(const float* __restrict__ S,
                                          const float* __restrict__ scale,
                                          float* __restrict__ out,
                                          int tid, int nthreads, int a, int b) {
  float th = (float)a * (float)(3.14159265358979323846 / 299.0);
  float c = cosf(th), s = sinf(th);
  float u = fabsf(c) + fabsf(s);        // bw = 2u
  float u2 = u * u;
  float e1 = exp2f(-2.0f * u2);
  float e2 = exp2f(-8.0f * u2);
  float norm = 1.0f / (1.0f + 2.0f * (e1 + e2));
  float w2c = norm, w1c = e1 * norm, w0c = e2 * norm;
  float sc = scale[b];
  const float* row = S + (a * NB + b) * NDET;
  float* orow = out + (b * NANG + a) * NDET;
  for (int j = tid; j < NDET; j += nthreads) {
    float acc = 0.f;
#pragma unroll
    for (int tt = -2; tt <= 2; ++tt) {
      int jr = j + tt;
      if (jr < 0) jr = -jr;
      if (jr > 299) jr = 598 - jr;
      float w = (tt == 0) ? w2c : ((tt == 1 || tt == -1) ? w1c : w0c);
      acc = fmaf(w, row[jr], acc);
    }
    orow[j] = acc * sc;
  }
}

// ---------------- fused persistent kernel (cooperative) ----------------
__global__ void __launch_bounds__(256, 3)
k_fused(const float* __restrict__ img, const float* __restrict__ att,
        const float* __restrict__ scale, uint4* __restrict__ Q,
        float* __restrict__ S, float* __restrict__ out) {
  __shared__ float sm[2704];            // P1: 10.8 KB staging ; P2: 4.35 KB coord pipe
  int tid = threadIdx.x;
  int vb  = blockIdx.x;
  cg::grid_group grid = cg::this_grid();

  // Phase 1: prep (1600 tiles, grid-strided)
  for (int vt = vb; vt < 1600; vt += GRID) {
    prep_tile(img, att, Q, sm, tid, (vt % 10) * 16, ((vt / 10) % 10) * 16, vt / 100);
    __syncthreads();                    // LDS safe before next tile
  }
  grid.sync();

  // Phase 2: radon (5700 tiles, grid-strided)
  for (int vt = vb; vt < 5700; vt += GRID) {
    int a = vt / 19;
    radon_tile(Q, S, (uint4*)sm, tid, a, vt - a * 19);
  }
  grid.sync();

  // Phase 3: dblur (4800 rows, grid-strided)
  for (int vt = vb; vt < 4800; vt += GRID)
    dblur_row(S, scale, out, tid, 256, vt % 300, vt / 300);
}

// ---------------- fallback kernels (r12-proven 3-dispatch path) ----------------
__global__ void k_prep(const float* __restrict__ img, const float* __restrict__ att,
                       uint4* __restrict__ Q) {
  __shared__ float sm[2704];
  prep_tile(img, att, Q, sm, threadIdx.x, blockIdx.x * 16, blockIdx.y * 16, blockIdx.z);
}

__global__ void __launch_bounds__(256)
k_radon(const uint4* __restrict__ Q, float* __restrict__ S) {
  __shared__ uint4 sLds[16 * 17];
  radon_tile(Q, S, sLds, threadIdx.x, blockIdx.y, blockIdx.x);
}

__global__ void k_dblur(const float* __restrict__ S, const float* __restrict__ scale,
                        float* __restrict__ out) {
  dblur_row(S, scale, out, threadIdx.x, 320, blockIdx.x, blockIdx.y);
}

extern "C" void kernel_launch(void* const* d_in, const int* in_sizes, int n_in,
                              void* d_out, int out_size, void* d_ws, size_t ws_size,
                              hipStream_t stream) {
  const float* img   = (const float*)d_in[0];
  const float* att   = (const float*)d_in[1];
  const float* scale = (const float*)d_in[2];
  float* out = (float*)d_out;
  float* ws  = (float*)d_ws;

  // ws layout (floats): Q 148*148*16 uint4 (5.61 MB) | S 300*300*16 (5.76 MB)
  uint4* Q = (uint4*)ws;
  float* S = ws + 1401856;

  void* args[] = { (void*)&img, (void*)&att, (void*)&scale,
                   (void*)&Q, (void*)&S, (void*)&out };
  hipError_t err = hipLaunchCooperativeKernel((const void*)k_fused,
                                              dim3(GRID), dim3(256),
                                              args, 0, stream);
  if (err != hipSuccess) {
    // fallback: proven 3-dispatch structure (~156 us)
    k_prep <<<dim3(10, 10, NB), 256, 0, stream>>>(img, att, Q);
    k_radon<<<dim3(19, NANG),   256, 0, stream>>>(Q, S);
    k_dblur<<<dim3(NANG, NB),   320, 0, stream>>>(S, scale, out);
  }
}